// Round 16
// baseline (171.569 us; speedup 1.0000x reference)
//
#include <hip/hip_runtime.h>

// out[b,p,c] = sum_s (x[b,s,c]-x[b,S-1,c]) * W[c,p,s] + bias[c,p] + x[b,S-1,c]
//   1) xpose: x'(c,b,s) = bf16(x[b,s,c]-x[b,S-1,c]) into d_ws (86 MB), linear.
//   2) gemm R16 = R15 with the W-register dataflow FIXED: each W set is
//      refilled inside comp*, AFTER the cvt consumes it (r15 clobbered set0
//      before compute -> chunk jj used chunk jj+2's weights). Wave = [128b x
//      16p] streams W HBM->regs privately (no LDS, no barrier coupling, read
//      once); A dbufs through 20 KB LDS in 8 KB chunks (lgkm-only barriers).

typedef __attribute__((ext_vector_type(8))) short short8;   // 8 bf16
typedef __attribute__((ext_vector_type(4))) float floatx4;  // MFMA C/D

namespace {
constexpr int Bn = 128, Sn = 672, Pn = 168, Cn = 500;
constexpr int XQ = Bn * Sn;           // ushorts per c-plane of x'
constexpr int TC = 64, TS = 96, TROW = TS + 12;   // xpose tile
constexpr int NS  = Sn / 32;          // 21 K-chunks (MFMA K=32)
constexpr int APITCH = 40;            // A LDS row pitch in ushorts (32 + 8 pad)
}

__device__ __forceinline__ unsigned short f2bf(float f) {  // RTNE f32->bf16
  unsigned int u = __builtin_bit_cast(unsigned int, f);
  u += 0x7fffu + ((u >> 16) & 1u);
  return (unsigned short)(u >> 16);
}

// ---------------------------------------------------------------- xpose ----
__global__ __launch_bounds__(256)
void xpose_kernel(const float* __restrict__ x, unsigned short* __restrict__ xq) {
  __shared__ unsigned short T[TC][TROW];
  const int b  = blockIdx.x;
  const int s0 = blockIdx.y * TS;
  const int c0 = blockIdx.z * TC;
  const int t  = threadIdx.x;

  #pragma unroll
  for (int i = 0; i < 6; ++i) {
    const int idx = t + i * 256;       // 96 s-rows x 16 c-quads
    const int sr  = idx >> 4;
    const int cq  = (idx & 15) * 4;
    int c = c0 + cq;
    if (c > Cn - 4) c = Cn - 4;        // clamp (16B-aligned); dup writes identical
    const int rel = c - c0;
    const float4 xv = *(const float4*)&x[(size_t)(b * Sn + s0 + sr) * Cn + c];
    const float4 xl = *(const float4*)&x[(size_t)(b * Sn + (Sn - 1)) * Cn + c];
    T[rel + 0][sr] = f2bf(xv.x - xl.x);
    T[rel + 1][sr] = f2bf(xv.y - xl.y);
    T[rel + 2][sr] = f2bf(xv.z - xl.z);
    T[rel + 3][sr] = f2bf(xv.w - xl.w);
  }
  __syncthreads();
  #pragma unroll
  for (int i = 0; i < 6; ++i) {
    const int idx = t + i * 256;       // 64 c-rows x 24 s-quads
    const int cr  = idx / 24;
    const int sq  = (idx % 24) * 4;
    const int c   = c0 + cr;
    if (c >= Cn) continue;
    const ushort4 v = *(const ushort4*)&T[cr][sq];
    *(ushort4*)&xq[(size_t)c * XQ + b * Sn + s0 + sq] = v;
  }
}

// ----------------------------------------------------------------- gemm ----
#define BAR_LGKM() asm volatile("s_waitcnt lgkmcnt(0)\n\ts_barrier" ::: "memory")

__global__ __launch_bounds__(704, 1)
void gemm_kernel(const unsigned short* __restrict__ xq, const float* __restrict__ W,
                 const float* __restrict__ bias, const float* __restrict__ x,
                 float* __restrict__ out) {
  __shared__ unsigned short Al[2][Bn * APITCH];   // 2 x 10.0 KB, pitch-40 rows
  __shared__ float xl_l[Bn];

  // bijective XCD remap: consecutive c-planes co-run on one XCD (write merge)
  const int bid = blockIdx.x;
  const int xcd = bid & 7, sub = bid >> 3;
  const int c0  = xcd * 62 + (xcd < 4 ? xcd : 4) + sub;   // 0..499

  const int tid  = threadIdx.x;
  const int lane = tid & 63;
  const int wv   = tid >> 6;           // 0..10 = p-tile of this wave
  const int r16  = lane & 15;
  const int kg   = lane >> 4;

  // ---- A staging role (tid < 512): b = tid>>2, k-octet = tid&3 ----
  const bool aDo = tid < 512;          // wave-uniform (waves 0..7)
  const int  ab  = (tid >> 2) & 127;
  const int  aoct = tid & 3;
  const unsigned short* aSrc = xq + (size_t)c0 * XQ + ab * Sn + aoct * 8;
  const int aDst = ab * APITCH + aoct * 8;

  // ---- W stream role: lane owns row p = wv*16 + r16, k-octet kg ----
  const int p   = wv * 16 + r16;
  const int pcl = p < Pn ? p : Pn - 1;
  const float* wSrc = W + ((size_t)c0 * Pn + pcl) * Sn + kg * 8;
  const float bi = bias[(size_t)c0 * Pn + pcl];

  if (tid < Bn) xl_l[tid] = x[((size_t)tid * Sn + (Sn - 1)) * Cn + c0];

  floatx4 acc[8];
  #pragma unroll
  for (int bs = 0; bs < 8; ++bs) acc[bs] = (floatx4){0.f, 0.f, 0.f, 0.f};

  // ---- static register sets (rule #20) ----
  short8 a0, a1;                       // A chunk staging (16 B/thread)
  float4 wA0, wB0, wA1, wB1;           // W depth-2 (2 float4 per chunk)

  auto lA0 = [&](int s) { if (aDo) a0 = *(const short8*)(aSrc + s * 32); };
  auto lA1 = [&](int s) { if (aDo) a1 = *(const short8*)(aSrc + s * 32); };
  auto lW0 = [&](int s) {
    wA0 = *(const float4*)(wSrc + s * 32);
    wB0 = *(const float4*)(wSrc + s * 32 + 4);
  };
  auto lW1 = [&](int s) {
    wA1 = *(const float4*)(wSrc + s * 32);
    wB1 = *(const float4*)(wSrc + s * 32 + 4);
  };
  auto wrA0 = [&](int buf) { if (aDo) *(short8*)&Al[buf][aDst] = a0; };
  auto wrA1 = [&](int buf) { if (aDo) *(short8*)&Al[buf][aDst] = a1; };

  // compute chunk from W set0; cvt FIRST, then refill set0 (data-dep safe)
  auto comp0 = [&](int buf, int nextS, bool reload) {
    short8 wb;
    wb[0] = (short)f2bf(wA0.x); wb[1] = (short)f2bf(wA0.y);
    wb[2] = (short)f2bf(wA0.z); wb[3] = (short)f2bf(wA0.w);
    wb[4] = (short)f2bf(wB0.x); wb[5] = (short)f2bf(wB0.y);
    wb[6] = (short)f2bf(wB0.z); wb[7] = (short)f2bf(wB0.w);
    if (reload) lW0(nextS);            // in flight through MFMAs + next phase
    #pragma unroll
    for (int bs = 0; bs < 8; ++bs) {
      const short8 af = *(const short8*)&Al[buf][(bs * 16 + r16) * APITCH + kg * 8];
      acc[bs] = __builtin_amdgcn_mfma_f32_16x16x32_bf16(af, wb, acc[bs], 0, 0, 0);
    }
  };
  auto comp1 = [&](int buf, int nextS, bool reload) {
    short8 wb;
    wb[0] = (short)f2bf(wA1.x); wb[1] = (short)f2bf(wA1.y);
    wb[2] = (short)f2bf(wA1.z); wb[3] = (short)f2bf(wA1.w);
    wb[4] = (short)f2bf(wB1.x); wb[5] = (short)f2bf(wB1.y);
    wb[6] = (short)f2bf(wB1.z); wb[7] = (short)f2bf(wB1.w);
    if (reload) lW1(nextS);
    #pragma unroll
    for (int bs = 0; bs < 8; ++bs) {
      const short8 af = *(const short8*)&Al[buf][(bs * 16 + r16) * APITCH + kg * 8];
      acc[bs] = __builtin_amdgcn_mfma_f32_16x16x32_bf16(af, wb, acc[bs], 0, 0, 0);
    }
  };

  // ---- prologue: chunks 0,1 in flight; stage chunk 0 ----
  lA0(0); lW0(0); lA1(1); lW1(1);
  wrA0(0);                             // counted wait on a0 (oldest); rest in flight
  BAR_LGKM();

  // ---- main loop: even chunk jj -> buf0/set0, odd jj+1 -> buf1/set1 ----
  #pragma unroll 1
  for (int jj = 0; jj < NS - 1; jj += 2) {
    // chunk jj
    lA0(jj + 2);                       // jj+2 <= 20 always (jj <= 18)
    wrA1(1);                           // stage chunk jj+1 (a1 loaded 1 period ago)
    comp0(0, jj + 2, true);            // cvt set0(jj) -> refill set0 <- jj+2 -> MFMA
    BAR_LGKM();
    // chunk jj+1
    if (jj + 3 < NS) lA1(jj + 3);
    wrA0(0);                           // stage chunk jj+2
    comp1(1, jj + 3, jj + 3 < NS);     // cvt set1(jj+1) -> refill set1 <- jj+3 -> MFMA
    BAR_LGKM();
  }
  comp0(0, 0, false);                  // chunk 20 (even, buf0, set0 holds 20)

  // ---- epilogue: out = acc + bias + xlast ----
  if (p < Pn) {
    #pragma unroll
    for (int bs = 0; bs < 8; ++bs) {
      #pragma unroll
      for (int r = 0; r < 4; ++r) {
        const int b = bs * 16 + kg * 4 + r;     // D row = kg*4 + reg
        out[((size_t)b * Pn + p) * Cn + c0] = acc[bs][r] + bi + xl_l[b];
      }
    }
  }
}

extern "C" void kernel_launch(void* const* d_in, const int* in_sizes, int n_in,
                              void* d_out, int out_size, void* d_ws, size_t ws_size,
                              hipStream_t stream) {
  (void)in_sizes; (void)n_in; (void)out_size; (void)ws_size;  // needs ws >= 86,016,000 B
  const float* x  = (const float*)d_in[0];
  const float* W  = (const float*)d_in[1];
  const float* bv = (const float*)d_in[2];
  float* out = (float*)d_out;
  unsigned short* xq = (unsigned short*)d_ws;

  hipLaunchKernelGGL(xpose_kernel, dim3(Bn, Sn / TS, (Cn + TC - 1) / TC), dim3(256), 0, stream,
                     x, xq);
  hipLaunchKernelGGL(gemm_kernel, dim3(Cn), dim3(704), 0, stream,
                     xq, W, bv, x, out);
}

// Round 17
// 155.906 us; speedup vs baseline: 1.1005x; 1.1005x over previous
//
#include <hip/hip_runtime.h>

// out[b,p,c] = sum_s (x[b,s,c]-x[b,S-1,c]) * W[c,p,s] + bias[c,p] + x[b,S-1,c]
//   1) xpose: x'(c,b,s) = bf16(x[b,s,c]-x[b,S-1,c]) into d_ws (86 MB), linear.
//   2) gemm R17 = R14 EXACTLY (best: 150.7 us) except the store target:
//      writes out_t[c][b*168+p] (coalesced 64B segments) instead of the
//      4B/lane stride-2000B scatter into out. A/B test of store-scatter cost.
//   3) otrans: out_t -> out transpose, 64x64 LDS tiles, coalesced both sides.
//   Falls back to r14-identical direct-store if ws_size < 129 MB.

typedef __attribute__((ext_vector_type(8))) short short8;   // 8 bf16
typedef __attribute__((ext_vector_type(4))) float floatx4;  // MFMA C/D

namespace {
constexpr int Bn = 128, Sn = 672, Pn = 168, Cn = 500;
constexpr int XQ = Bn * Sn;           // ushorts per c-plane of x'
constexpr int BP = Bn * Pn;           // 21504 outputs per c-plane
constexpr int TC = 64, TS = 96, TROW = TS + 12;   // xpose tile
constexpr int NS  = Sn / 32;          // 21 s-chunks (MFMA K=32)
constexpr int NPT = 11;               // p-tiles of 16 (last half-masked)
constexpr int WROW = 680;             // LDS W row pitch in ushorts (672+8 pad)
constexpr size_t XQ_BYTES = (size_t)Cn * XQ * 2;        // 86,016,000
constexpr size_t WS_NEED  = XQ_BYTES + (size_t)Cn * BP * 4;  // + 43,008,000
}

__device__ __forceinline__ unsigned short f2bf(float f) {  // RTNE f32->bf16
  unsigned int u = __builtin_bit_cast(unsigned int, f);
  u += 0x7fffu + ((u >> 16) & 1u);
  return (unsigned short)(u >> 16);
}

// ---------------------------------------------------------------- xpose ----
__global__ __launch_bounds__(256)
void xpose_kernel(const float* __restrict__ x, unsigned short* __restrict__ xq) {
  __shared__ unsigned short T[TC][TROW];
  const int b  = blockIdx.x;
  const int s0 = blockIdx.y * TS;
  const int c0 = blockIdx.z * TC;
  const int t  = threadIdx.x;

  #pragma unroll
  for (int i = 0; i < 6; ++i) {
    const int idx = t + i * 256;       // 96 s-rows x 16 c-quads
    const int sr  = idx >> 4;
    const int cq  = (idx & 15) * 4;
    int c = c0 + cq;
    if (c > Cn - 4) c = Cn - 4;        // clamp (16B-aligned); dup writes identical
    const int rel = c - c0;
    const float4 xv = *(const float4*)&x[(size_t)(b * Sn + s0 + sr) * Cn + c];
    const float4 xl = *(const float4*)&x[(size_t)(b * Sn + (Sn - 1)) * Cn + c];
    T[rel + 0][sr] = f2bf(xv.x - xl.x);
    T[rel + 1][sr] = f2bf(xv.y - xl.y);
    T[rel + 2][sr] = f2bf(xv.z - xl.z);
    T[rel + 3][sr] = f2bf(xv.w - xl.w);
  }
  __syncthreads();
  #pragma unroll
  for (int i = 0; i < 6; ++i) {
    const int idx = t + i * 256;       // 64 c-rows x 24 s-quads
    const int cr  = idx / 24;
    const int sq  = (idx % 24) * 4;
    const int c   = c0 + cr;
    if (c >= Cn) continue;
    const ushort4 v = *(const ushort4*)&T[cr][sq];
    *(ushort4*)&xq[(size_t)c * XQ + b * Sn + s0 + sq] = v;
  }
}

// ----------------------------------------------------------------- gemm ----
#define BAR_LGKM() asm volatile("s_waitcnt lgkmcnt(0)\n\ts_barrier" ::: "memory")

template <bool TO_WS>
__global__ __launch_bounds__(512, 2)   // proven no-spill config (r10/r12/r14)
void gemm_kernel(const unsigned short* __restrict__ xq, const float* __restrict__ W,
                 const float* __restrict__ bias, const float* __restrict__ x,
                 float* __restrict__ out, float* __restrict__ ot) {
  __shared__ unsigned short Wl[2][16 * WROW];   // 2 x 21.25 KB bf16, padded rows
  __shared__ float xl_l[Bn];
  __shared__ float bi_l[Pn];

  // bijective XCD remap: consecutive c-planes co-run on one XCD
  const int bid = blockIdx.x;
  const int xcd = bid & 7, sub = bid >> 3;
  const int c0  = xcd * 62 + (xcd < 4 ? xcd : 4) + sub;   // 0..499

  const int tid  = threadIdx.x;
  const int lane = tid & 63;
  const int wv   = tid >> 6;           // wave owns b in [16*wv, 16*wv+16)
  const int r16  = lane & 15;
  const int kg   = lane >> 4;

  // ---- W staging descriptors: 2688 float4 per p-tile, 6 per thread ----
  int wrow[6], wcol[6];
  #pragma unroll
  for (int k = 0; k < 6; ++k) {
    const int f = tid + 512 * k;
    wrow[k] = f / 168;
    wcol[k] = f % 168;
  }
  const bool w5 = tid < 128;           // 2688 = 5*512 + 128

  float4 w0[6], w1[6];                 // two static prefetch sets

  auto loadW0 = [&](int pt) {
    #pragma unroll
    for (int k = 0; k < 6; ++k) {
      if (k == 5 && !w5) continue;
      int row = pt * 16 + wrow[k];
      if (row > Pn - 1) row = Pn - 1;
      w0[k] = *(const float4*)&W[((size_t)c0 * Pn + row) * Sn + wcol[k] * 4];
    }
  };
  auto loadW1 = [&](int pt) {
    #pragma unroll
    for (int k = 0; k < 6; ++k) {
      if (k == 5 && !w5) continue;
      int row = pt * 16 + wrow[k];
      if (row > Pn - 1) row = Pn - 1;
      w1[k] = *(const float4*)&W[((size_t)c0 * Pn + row) * Sn + wcol[k] * 4];
    }
  };
  auto writeW0 = [&](int buf) {
    #pragma unroll
    for (int k = 0; k < 6; ++k) {
      if (k == 5 && !w5) continue;
      ushort4 u;
      u.x = f2bf(w0[k].x); u.y = f2bf(w0[k].y);
      u.z = f2bf(w0[k].z); u.w = f2bf(w0[k].w);
      *(ushort4*)&Wl[buf][wrow[k] * WROW + wcol[k] * 4] = u;
    }
  };
  auto writeW1 = [&](int buf) {
    #pragma unroll
    for (int k = 0; k < 6; ++k) {
      if (k == 5 && !w5) continue;
      ushort4 u;
      u.x = f2bf(w1[k].x); u.y = f2bf(w1[k].y);
      u.z = f2bf(w1[k].z); u.w = f2bf(w1[k].w);
      *(ushort4*)&Wl[buf][wrow[k] * WROW + wcol[k] * 4] = u;
    }
  };

  // ---- compute + per-tile epilogue ----
  const unsigned short* aBase = xq + (size_t)c0 * XQ + (wv * 16 + r16) * Sn + kg * 8;
  short8 aR[NS];                        // 84 VGPR, resident for whole kernel
  auto tile = [&](int pt, int buf) {
    floatx4 acc = (floatx4){0.f, 0.f, 0.f, 0.f};
    const int rdb = r16 * WROW + kg * 8;
    #pragma unroll
    for (int s = 0; s < NS; ++s) {
      const short8 wf = *(const short8*)&Wl[buf][rdb + s * 32];
      acc = __builtin_amdgcn_mfma_f32_16x16x32_bf16(aR[s], wf, acc, 0, 0, 0);
    }
    const int p = pt * 16 + r16;        // D col = r16 (=p), row = kg*4 + r
    if (p < Pn) {
      const float bi = bi_l[p];
      #pragma unroll
      for (int r = 0; r < 4; ++r) {
        const int b = wv * 16 + kg * 4 + r;
        const float v = acc[r] + bi + xl_l[b];
        if (TO_WS) ot[(size_t)c0 * BP + b * Pn + p] = v;   // coalesced 64B segs
        else       out[((size_t)b * Pn + p) * Cn + c0] = v; // r14 scatter path
      }
    }
  };

  // ---- prologue ----
  loadW0(0);
  loadW1(1);
  if (tid < Bn) xl_l[tid] = x[((size_t)tid * Sn + (Sn - 1)) * Cn + c0];
  else if (tid < Bn + Pn) bi_l[tid - Bn] = bias[(size_t)c0 * Pn + (tid - Bn)];
  #pragma unroll
  for (int s = 0; s < NS; ++s) aR[s] = *(const short8*)(aBase + s * 32);
  writeW0(0);                           // counted wait on w0; w1 + aR in flight
  BAR_LGKM();

  // ---- main loop: pairs (even=buf0/set0, odd=buf1/set1), NPT = 11 ----
  #pragma unroll 1
  for (int jj = 0; jj < NPT - 1; jj += 2) {
    writeW1(1);                         // waits w1: issued >= 1 tile period ago
    loadW0(jj + 2);
    tile(jj, 0);
    BAR_LGKM();
    writeW0(0);
    if (jj + 3 < NPT) loadW1(jj + 3);
    tile(jj + 1, 1);
    BAR_LGKM();
  }
  tile(NPT - 1, 0);                     // pt = 10
}

// ---------------------------------------------------------------- otrans ----
// out[bp][c] = ot[c][bp]. 64x64 tiles, both sides coalesced, stride-69 LDS.
__global__ __launch_bounds__(256)
void otrans_kernel(const float* __restrict__ ot, float* __restrict__ out) {
  __shared__ float T[64][69];
  const int bp0 = blockIdx.x * 64;      // 21504 = 336 * 64 exact
  const int c0  = blockIdx.y * 64;      // 500 = 7*64 + 52 (partial last)
  const int t   = threadIdx.x;
  const int rr  = t >> 4;               // 0..15
  const int qq  = t & 15;               // float4 index

  #pragma unroll
  for (int i = 0; i < 4; ++i) {
    const int cr = rr + i * 16;         // c-row within tile
    if (c0 + cr < Cn) {
      const float4 v = *(const float4*)&ot[(size_t)(c0 + cr) * BP + bp0 + qq * 4];
      T[cr][qq * 4 + 0] = v.x;
      T[cr][qq * 4 + 1] = v.y;
      T[cr][qq * 4 + 2] = v.z;
      T[cr][qq * 4 + 3] = v.w;
    }
  }
  __syncthreads();
  #pragma unroll
  for (int i = 0; i < 4; ++i) {
    const int br = rr + i * 16;         // bp-row within tile
    const int cq = qq * 4;
    if (c0 + cq + 3 < Cn) {             // last tile: 52 = 13*4 exact
      float4 v;
      v.x = T[cq + 0][br]; v.y = T[cq + 1][br];
      v.z = T[cq + 2][br]; v.w = T[cq + 3][br];
      *(float4*)&out[(size_t)(bp0 + br) * Cn + c0 + cq] = v;
    }
  }
}

extern "C" void kernel_launch(void* const* d_in, const int* in_sizes, int n_in,
                              void* d_out, int out_size, void* d_ws, size_t ws_size,
                              hipStream_t stream) {
  (void)in_sizes; (void)n_in; (void)out_size;
  const float* x  = (const float*)d_in[0];
  const float* W  = (const float*)d_in[1];
  const float* bv = (const float*)d_in[2];
  float* out = (float*)d_out;
  unsigned short* xq = (unsigned short*)d_ws;
  float* ot = (float*)((char*)d_ws + XQ_BYTES);

  hipLaunchKernelGGL(xpose_kernel, dim3(Bn, Sn / TS, (Cn + TC - 1) / TC), dim3(256), 0, stream,
                     x, xq);
  if (ws_size >= WS_NEED) {
    hipLaunchKernelGGL(gemm_kernel<true>, dim3(Cn), dim3(512), 0, stream,
                       xq, W, bv, x, out, ot);
    hipLaunchKernelGGL(otrans_kernel, dim3(BP / 64, (Cn + 63) / 64), dim3(256), 0, stream,
                       ot, out);
  } else {
    hipLaunchKernelGGL(gemm_kernel<false>, dim3(Cn), dim3(512), 0, stream,
                       xq, W, bv, x, out, ot);
  }
}